// Round 1
// baseline (4619.942 us; speedup 1.0000x reference)
//
#include <hip/hip_runtime.h>
#include <hip/hip_cooperative_groups.h>

namespace cg = cooperative_groups;

#define NN   4096
#define TT   17
#define NTOT (NN*TT)          // 69632
#define EPS_F  1e-10f
#define EPS2_F 1e-20f
#define NBLK 256
#define NTHR 512
#define TK   256
#define RPB  16               // rows of K per block

// ws layout (floats): r[NTOT] p[NTOT] q[NTOT] x[NTOT] gam[48*17] den[48*17] ssq[17] rhs[17] conv[17]

__global__ __launch_bounds__(NTHR, 2)
void gp_cg_kernel(const float* __restrict__ Km, const float* __restrict__ yv,
                  const float* __restrict__ Zm, const float* __restrict__ noise,
                  const int* __restrict__ cg_iters, float* __restrict__ out,
                  float* __restrict__ ws)
{
    cg::grid_group grid = cg::this_grid();
    const int tid  = threadIdx.x;
    const int b    = blockIdx.x;
    const int lane = tid & 63;

    float* r_  = ws;
    float* p_  = r_ + NTOT;
    float* q_  = p_ + NTOT;
    float* x_  = q_ + NTOT;
    float* gam = x_ + NTOT;        // [48][17]
    float* den = gam + 48*TT;      // [48][17]
    float* ssq = den + 48*TT;      // [17]
    float* rhs = ssq + TT;         // [17]
    float* cvf = rhs + TT;         // [17] conv flags (0/1)

    const float sigma2 = noise[0]*noise[0];
    const int   niters = cg_iters[0];

    __shared__ float r_lds[2][TK*TT];      // double-buffered r tile, [k][c], 34 KB
    __shared__ float ap_lds[RPB*TT];       // K*r sums per (row,col)
    __shared__ float dn_lds[TT];
    __shared__ float rd_lds[NTHR/64];

    // ---- S0: zero scalars (gam..cvf contiguous) and x, q ----
    for (int i = b*NTHR + tid; i < 48*TT*2 + 3*TT; i += NBLK*NTHR) gam[i] = 0.f;
    for (int i = b*NTHR + tid; i < NTOT; i += NBLK*NTHR) { x_[i] = 0.f; q_[i] = 0.f; }
    grid.sync();

    // ---- S1: per-column sum of squares of [y | Z] ----
    if (tid < TT) dn_lds[tid] = 0.f;
    __syncthreads();
    if (tid < RPB*TT) {
        int n = b*RPB + tid/TT;
        int c = tid % TT;
        float v = (c == 0) ? yv[n] : Zm[n*(TT-1) + (c-1)];
        atomicAdd(&dn_lds[c], v*v);
    }
    __syncthreads();
    if (tid < TT) atomicAdd(&ssq[tid], dn_lds[tid]);
    grid.sync();

    // ---- S2: build b_norm -> r0, p0; gamma0, rhs_norm, conv0 ----
    for (int e = b*NTHR + tid; e < NTOT; e += NBLK*NTHR) {
        int c = e >> 12, n = e & (NN-1);
        float sc = ssq[c];
        float scale, rh;
        if (c == 0) {
            rh = sqrtf(sc); if (rh < EPS_F) rh = 1.f;
            scale = 1.f/rh;
        } else {
            float zn = sqrtf(sc);
            float bn = zn/(zn + EPS_F);          // ||Z/(||Z||+eps)||
            rh = (bn < EPS_F) ? 1.f : bn;
            scale = 1.f/((zn + EPS_F)*rh);
        }
        float raw = (c == 0) ? yv[n] : Zm[n*(TT-1) + (c-1)];
        float v = raw*scale;
        r_[e] = v; p_[e] = v;
        if (n == 0) {
            rhs[c] = rh;
            float g0 = sc*scale*scale;           // = ||b_norm||^2
            gam[c] = g0;
            cvf[c] = (g0 < EPS2_F) ? 1.f : 0.f;
        }
    }
    grid.sync();

    const int rg = tid >> 7;          // row group 0..3 (4 rows each)
    const int ks = tid & 127;         // k-slice
    const int row0 = b*RPB + rg*4;

    for (int it = 0; it < niters; ++it) {
        // ================= Phase A: Ar GEMM + p/q recurrence + denom =================
        float acc[4][TT];
        #pragma unroll
        for (int rr = 0; rr < 4; ++rr)
            #pragma unroll
            for (int c = 0; c < TT; ++c) acc[rr][c] = 0.f;

        // stage tile 0
        for (int v = tid; v < (TK/4)*TT; v += NTHR) {
            int c = v >> 6, k4 = (v & 63) << 2;
            float4 f = *(const float4*)(r_ + c*NN + k4);
            float* dst = r_lds[0];
            dst[(k4+0)*TT + c] = f.x;
            dst[(k4+1)*TT + c] = f.y;
            dst[(k4+2)*TT + c] = f.z;
            dst[(k4+3)*TT + c] = f.w;
        }
        float2 kv[4], kvn[4];
        #pragma unroll
        for (int rr = 0; rr < 4; ++rr)
            kv[rr] = *(const float2*)(Km + (size_t)(row0+rr)*NN + 2*ks);
        #pragma unroll
        for (int rr = 0; rr < 4; ++rr) kvn[rr] = kv[rr];
        __syncthreads();

        for (int tt = 0; tt < NN/TK; ++tt) {
            if (tt + 1 < NN/TK) {
                int kb = (tt+1)*TK;
                for (int v = tid; v < (TK/4)*TT; v += NTHR) {
                    int c = v >> 6, k4 = (v & 63) << 2;
                    float4 f = *(const float4*)(r_ + c*NN + kb + k4);
                    float* dst = r_lds[(tt+1) & 1];
                    dst[(k4+0)*TT + c] = f.x;
                    dst[(k4+1)*TT + c] = f.y;
                    dst[(k4+2)*TT + c] = f.z;
                    dst[(k4+3)*TT + c] = f.w;
                }
                #pragma unroll
                for (int rr = 0; rr < 4; ++rr)
                    kvn[rr] = *(const float2*)(Km + (size_t)(row0+rr)*NN + kb + 2*ks);
            }
            const float* rl = r_lds[tt & 1] + 34*ks;   // k0 = 2*ks
            #pragma unroll
            for (int c = 0; c < TT; ++c) {
                float a0 = rl[c], a1 = rl[c + TT];
                #pragma unroll
                for (int rr = 0; rr < 4; ++rr)
                    acc[rr][c] += kv[rr].x*a0 + kv[rr].y*a1;
            }
            #pragma unroll
            for (int rr = 0; rr < 4; ++rr) kv[rr] = kvn[rr];
            __syncthreads();
        }

        // zero combine buffers
        if (tid < RPB*TT) ap_lds[tid] = 0.f;
        if (tid < TT) dn_lds[tid] = 0.f;
        __syncthreads();

        // reduce k-split: 64-lane butterfly, then LDS atomic across the 2 waves/row-group
        #pragma unroll
        for (int rr = 0; rr < 4; ++rr)
            #pragma unroll
            for (int c = 0; c < TT; ++c) {
                float v = acc[rr][c];
                v += __shfl_xor(v, 1, 64);
                v += __shfl_xor(v, 2, 64);
                v += __shfl_xor(v, 4, 64);
                v += __shfl_xor(v, 8, 64);
                v += __shfl_xor(v, 16, 64);
                v += __shfl_xor(v, 32, 64);
                acc[rr][c] = v;
            }
        #pragma unroll
        for (int rr = 0; rr < 4; ++rr) {
            #pragma unroll
            for (int c = 0; c < TT; ++c) {
                if (lane == c)
                    atomicAdd(&ap_lds[(rg*4+rr)*TT + c], acc[rr][c]);
            }
        }
        __syncthreads();

        // per-element epilogue: Ar, beta, p/q recurrence, denom partial
        if (tid < RPB*TT) {
            int rl_i = tid / TT, c = tid % TT;
            int n = b*RPB + rl_i;
            int idx = c*NN + n;
            float kr = ap_lds[tid];
            float rv = r_[idx];
            float Ar = kr + sigma2*rv;
            float beta = 0.f;
            if (it > 0) {
                float g1 = gam[it*TT + c], g0 = gam[(it-1)*TT + c];
                beta = (fabsf(g0) < EPS_F) ? 0.f : g1/g0;
            }
            float pn = rv + beta*p_[idx];
            float qn = Ar + beta*q_[idx];
            p_[idx] = pn;
            q_[idx] = qn;
            atomicAdd(&dn_lds[c], pn*qn);
        }
        __syncthreads();
        if (tid < TT) atomicAdd(&den[it*TT + tid], dn_lds[tid]);
        grid.sync();

        // ================= Phase B: alpha, x/r update, gamma_new =================
        if (b < NTOT/NTHR) {               // 136 blocks; each block = one c, 512 consecutive n
            int e = b*NTHR + tid;
            int c = e >> 12, n = e & (NN-1);
            float g  = gam[it*TT + c];
            float d0 = den[it*TT + c];
            bool  convb = (cvf[c] != 0.f) || (g < EPS2_F);
            bool  dz = fabsf(d0) < EPS_F;
            float alpha = (dz || convb) ? 0.f : g/d0;
            float pv = p_[e], qv = q_[e];
            float xn = x_[e] + alpha*pv;
            float rn = r_[e] - alpha*qv;
            x_[e] = xn;
            r_[e] = rn;
            if (it == niters - 1) out[n*TT + c] = xn*rhs[c];
            float v = rn*rn;
            v += __shfl_xor(v, 1, 64);
            v += __shfl_xor(v, 2, 64);
            v += __shfl_xor(v, 4, 64);
            v += __shfl_xor(v, 8, 64);
            v += __shfl_xor(v, 16, 64);
            v += __shfl_xor(v, 32, 64);
            if (lane == 0) rd_lds[tid >> 6] = v;
            __syncthreads();
            if (tid == 0) {
                float s = 0.f;
                #pragma unroll
                for (int w = 0; w < NTHR/64; ++w) s += rd_lds[w];
                atomicAdd(&gam[(it+1)*TT + c], s);
                if (n == 0) cvf[c] = convb ? 1.f : 0.f;   // persist conv (monotone OR)
            }
        }
        grid.sync();
    }
}

extern "C" void kernel_launch(void* const* d_in, const int* in_sizes, int n_in,
                              void* d_out, int out_size, void* d_ws, size_t ws_size,
                              hipStream_t stream) {
    const float* Km    = (const float*)d_in[0];
    const float* yv    = (const float*)d_in[1];
    const float* Zm    = (const float*)d_in[2];
    const float* noise = (const float*)d_in[3];
    const int*   iters = (const int*)d_in[4];
    float* out = (float*)d_out;
    float* ws  = (float*)d_ws;

    void* args[] = { &Km, &yv, &Zm, &noise, &iters, &out, &ws };
    hipLaunchCooperativeKernel((void*)gp_cg_kernel, dim3(NBLK), dim3(NTHR),
                               args, 0, stream);
}